// Round 7
// baseline (2816.492 us; speedup 1.0000x reference)
//
#include <hip/hip_runtime.h>
#include <math.h>
#include <stdint.h>

// ---------------- problem constants ----------------
constexpr int kL = 6;
constexpr int kE = 1024;
constexpr int kH = 16;
constexpr int kF = 4096;
constexpr int kV = 1024;
constexpr int kB = 4;
constexpr int kS = 1024;
constexpr int kRows = kB * kS;   // 4096

typedef __bf16 bf16_t;
typedef __bf16 bf16x8 __attribute__((ext_vector_type(8)));
typedef __bf16 bf16x4 __attribute__((ext_vector_type(4)));
typedef float f32x4 __attribute__((ext_vector_type(4)));
typedef unsigned int u32x2 __attribute__((ext_vector_type(2)));

#define AS1 __attribute__((address_space(1)))
#define AS3 __attribute__((address_space(3)))

__device__ __forceinline__ void gload_lds16(const void* g, void* l) {
  __builtin_amdgcn_global_load_lds((const AS1 unsigned int*)g, (AS3 unsigned int*)l, 16, 0, 0);
}

__device__ __forceinline__ unsigned lds_u32(const void* p) {
  return (unsigned)(uintptr_t)p;
}

__device__ __forceinline__ float gelu_f(float x) {
  return 0.5f * x * (1.0f + erff(x * 0.70710678118654752440f));
}

// DPP row-rotate (16-lane granularity). CTRL = 0x120 + n for ROW_ROR:n.
template <int CTRL>
__device__ __forceinline__ float dppf(float v) {
  return __builtin_bit_cast(float, __builtin_amdgcn_update_dpp(
      __builtin_bit_cast(int, v), __builtin_bit_cast(int, v), CTRL, 0xF, 0xF, false));
}

// ---------------- f32 -> bf16 cast ----------------
__global__ void cast_kernel(const float* __restrict__ in, bf16_t* __restrict__ out, int n4) {
  const int stride = gridDim.x * blockDim.x;
  for (int i = blockIdx.x * blockDim.x + threadIdx.x; i < n4; i += stride) {
    const float4 v = *(const float4*)(in + (size_t)i * 4);
    bf16x4 o;
    o[0] = (bf16_t)v.x; o[1] = (bf16_t)v.y; o[2] = (bf16_t)v.z; o[3] = (bf16_t)v.w;
    *(bf16x4*)(out + (size_t)i * 4) = o;
  }
}

// ---------------- embedding ----------------
__global__ void embed_kernel(const int* __restrict__ seq, const float* __restrict__ emb,
                             const float* __restrict__ pos, float* __restrict__ x32,
                             bf16_t* __restrict__ xb) {
  const int r = blockIdx.x;
  const int s = r & 1023;
  const int tok = seq[r];
  const int c = threadIdx.x << 2;
  const float4 e = *(const float4*)(emb + (size_t)tok * kE + c);
  const float4 pz = *(const float4*)(pos + (size_t)s * kE + c);
  float4 v;
  v.x = e.x * 32.0f + pz.x;
  v.y = e.y * 32.0f + pz.y;
  v.z = e.z * 32.0f + pz.z;
  v.w = e.w * 32.0f + pz.w;
  *(float4*)(x32 + (size_t)r * kE + c) = v;
  bf16x4 o;
  o[0] = (bf16_t)v.x; o[1] = (bf16_t)v.y; o[2] = (bf16_t)v.z; o[3] = (bf16_t)v.w;
  *(bf16x4*)(xb + (size_t)r * kE + c) = o;
}

// ---------------- residual add + LayerNorm ----------------
// MODE 0: x32 = LN(x32 + res_bf16), write bf16 copy.
// MODE 1: bf16 out only, no residual (final LN).
// MODE 2: x32 = LN(x32 + sum of 4 bf16 partials + bias2), write bf16 copy.
template <int MODE>
__global__ void addln_kernel(float* __restrict__ x32, const void* __restrict__ res,
                             const float* __restrict__ gg, const float* __restrict__ bb,
                             bf16_t* __restrict__ xb, const float* __restrict__ bias2) {
  __shared__ float red[8];
  const int r = blockIdx.x;
  const int c = threadIdx.x << 2;
  float4 v = *(const float4*)(x32 + (size_t)r * kE + c);
  if (MODE == 0) {
    const bf16x4 t = *(const bf16x4*)((const bf16_t*)res + (size_t)r * kE + c);
    v.x += (float)t[0]; v.y += (float)t[1]; v.z += (float)t[2]; v.w += (float)t[3];
  }
  if (MODE == 2) {
    const bf16_t* p = (const bf16_t*)res;
#pragma unroll
    for (int part = 0; part < 4; ++part) {
      const bf16x4 t = *(const bf16x4*)(p + (size_t)part * kRows * kE + (size_t)r * kE + c);
      v.x += (float)t[0]; v.y += (float)t[1]; v.z += (float)t[2]; v.w += (float)t[3];
    }
    const float4 b2 = *(const float4*)(bias2 + c);
    v.x += b2.x; v.y += b2.y; v.z += b2.z; v.w += b2.w;
  }
  float s = v.x + v.y + v.z + v.w;
  float q = v.x * v.x + v.y * v.y + v.z * v.z + v.w * v.w;
#pragma unroll
  for (int off = 32; off >= 1; off >>= 1) {
    s += __shfl_xor(s, off, 64);
    q += __shfl_xor(q, off, 64);
  }
  const int w = threadIdx.x >> 6, lane = threadIdx.x & 63;
  if (lane == 0) { red[w] = s; red[4 + w] = q; }
  __syncthreads();
  s = red[0] + red[1] + red[2] + red[3];
  q = red[4] + red[5] + red[6] + red[7];
  const float mean = s * (1.0f / 1024.0f);
  const float var = q * (1.0f / 1024.0f) - mean * mean;
  const float rstd = rsqrtf(var + 1e-5f);
  const float4 g4 = *(const float4*)(gg + c);
  const float4 b4 = *(const float4*)(bb + c);
  float4 o;
  o.x = (v.x - mean) * rstd * g4.x + b4.x;
  o.y = (v.y - mean) * rstd * g4.y + b4.y;
  o.z = (v.z - mean) * rstd * g4.z + b4.z;
  o.w = (v.w - mean) * rstd * g4.w + b4.w;
  if (MODE != 1) *(float4*)(x32 + (size_t)r * kE + c) = o;
  bf16x4 ob;
  ob[0] = (bf16_t)o.x; ob[1] = (bf16_t)o.y; ob[2] = (bf16_t)o.z; ob[3] = (bf16_t)o.w;
  *(bf16x4*)(xb + (size_t)r * kE + c) = ob;
}

// ---------------- GEMM 128x128, BK=32, 4 waves (v7: zero-LDS register streaming) ---
// Diagnosis R2-R6: four schedule variants (256² 8-phase, 2-barrier, triple-buf,
// counted-vmcnt dbuf) ALL converge to ~600 TF -> limiter is the per-CU LDS pipe
// (48 KB LDS traffic per 1-MFLOP block-iter), not scheduling. v7 removes LDS
// entirely: MFMA fragments load DIRECTLY global->VGPR. The fragment pattern
// (16 rows x 16B per lane-group) costs the same 16 line-requests/instr as a
// coalesced b128. Wave pairs (w0/w1 share A rows, w0/w2 share B rows) hit L1.
// No barriers at all -> waves free-run; compiler software-pipelines the
// register loads across iterations (unroll 2).
// EPI: 0 = bias->bf16, 1 = bias->f32 (logits), 2 = bias+GELU->bf16,
//      3 = no-bias->bf16 partial at Cv + blockIdx.z*zstride.
template <int EPI>
__launch_bounds__(256, 3)
__global__ void gemm128_kernel(const bf16_t* __restrict__ A, const bf16_t* __restrict__ Bt,
                               const float* __restrict__ bias, void* __restrict__ Cv,
                               int ldA, int ldB, int ldC, int kc, size_t zstride) {
  const int tid = threadIdx.x;
  const int w = tid >> 6;
  const int lane = tid & 63;
  const int g = lane >> 4;
  const int lr = lane & 15;

  // T1: XCD-aware bijective swizzle over (x,y); all grids have nwg % 8 == 0.
  const int nwg = gridDim.x * gridDim.y;
  const int lin = blockIdx.y * gridDim.x + blockIdx.x;
  const int cpx = nwg >> 3;
  const int swz = (lin & 7) * cpx + (lin >> 3);
  const int bx = swz % gridDim.x, by = swz / gridDim.x;
  const int bm0 = by << 7;
  const int bn0 = bx << 7;
  const int k0 = blockIdx.z * kc;
  const int wm = (w >> 1) << 6;
  const int wn = (w & 1) << 6;

  f32x4 zz = {0.f, 0.f, 0.f, 0.f};
  f32x4 acc[4][4];
#pragma unroll
  for (int i = 0; i < 4; ++i)
#pragma unroll
    for (int j = 0; j < 4; ++j) acc[i][j] = zz;

  // direct fragment pointers: lane (g, lr) of wave w reads
  // A row bm0+wm+i*16+lr, k = k0 + t*32 + g*8   (16B per lane)
  const bf16_t* pa[4];
  const bf16_t* pb[4];
#pragma unroll
  for (int i = 0; i < 4; ++i) {
    pa[i] = A + (size_t)(bm0 + wm + i * 16 + lr) * ldA + k0 + g * 8;
    pb[i] = Bt + (size_t)(bn0 + wn + i * 16 + lr) * ldB + k0 + g * 8;
  }

  const int NT = kc >> 5;
#pragma unroll 2
  for (int t = 0; t < NT; ++t) {
    bf16x8 a[4], b[4];
#pragma unroll
    for (int i = 0; i < 4; ++i) { a[i] = *(const bf16x8*)pa[i]; pa[i] += 32; }
#pragma unroll
    for (int i = 0; i < 4; ++i) { b[i] = *(const bf16x8*)pb[i]; pb[i] += 32; }
#pragma unroll
    for (int i = 0; i < 4; ++i)
#pragma unroll
      for (int j = 0; j < 4; ++j)
        acc[i][j] = __builtin_amdgcn_mfma_f32_16x16x32_bf16(a[i], b[j], acc[i][j], 0, 0, 0);
  }

  // epilogue: C/D layout col = lane&15, row = (lane>>4)*4 + reg
  bf16_t* outb = (bf16_t*)Cv;
  if (EPI == 3) outb += (size_t)blockIdx.z * zstride;
#pragma unroll
  for (int i = 0; i < 4; ++i) {
#pragma unroll
    for (int j = 0; j < 4; ++j) {
      const int col = bn0 + wn + j * 16 + lr;
      float bv = 0.0f;
      if (EPI != 3) bv = bias[col];
#pragma unroll
      for (int rg = 0; rg < 4; ++rg) {
        const int row = bm0 + wm + i * 16 + g * 4 + rg;
        float v = acc[i][j][rg] + bv;
        if (EPI == 2) v = gelu_f(v);
        if (EPI == 1) {
          ((float*)Cv)[(size_t)row * ldC + col] = v;
        } else {
          outb[(size_t)row * ldC + col] = (bf16_t)v;
        }
      }
    }
  }
}

// ---------------- fused causal attention with relative-distance bias ----------------
// v3: KVBLK=64 + DPP softmax reductions. Unchanged this round.
__launch_bounds__(256, 3)
__global__ void attn_kernel(const bf16_t* __restrict__ qkv, const int* __restrict__ seq,
                            const float* __restrict__ dist_emb, bf16_t* __restrict__ ctx) {
  __shared__ float sbias[1024];
  __shared__ unsigned char spad[1024];
  __shared__ bf16_t kbuf[2][64 * 64];
  __shared__ bf16_t vbuf[2][4096];
  __shared__ bf16_t pbuf[4][16][72];
  const int tid = threadIdx.x;
  const int w = tid >> 6, lane = tid & 63, g = lane >> 4, lr = lane & 15;
  const int bid = blockIdx.x;
  const int qt = 15 - (bid >> 6);      // heavy blocks dispatch first
  const int h = bid & 15, b = (bid >> 4) & 3;

  const int q0 = qt * 64 + w * 16;
  const bf16_t* qp = qkv + ((size_t)(b * kS + q0 + lr)) * 3072 + h * 64;

  // V staging source (tr-read layout, 32-row half granularity)
  const int p = (w * 64 + lane) * 16;
  const int s_kv = ((p >> 11) << 4) + ((p >> 5) & 15);
  const int s_dv = (((p >> 9) & 3) << 4) + ((p & 31) >> 1);
  const bf16_t* vsrc0 = qkv + ((size_t)(b * kS + s_kv)) * 3072 + 2048 + h * 64 + s_dv;

  // K staging source (xor-swizzle pre-applied to global column granule)
  const int klrow = (w << 3) + (lane >> 3);
  const int kscol = ((lane & 7) ^ (lane >> 3)) << 3;
  const bf16_t* ksrc0 = qkv + ((size_t)(b * kS + klrow)) * 3072 + 1024 + h * 64 + kscol;

  // swizzled K ds_read column offsets (elements)
  const int cs0k = (g ^ (lr & 7)) << 3;
  const int cs1k = ((4 + g) ^ (lr & 7)) << 3;

  const int* seqb = seq + b * kS;
  const int nt = qt + 1;

#define STAGEKV(bufi, kt_) {                                                        \
    gload_lds16(ksrc0 + (size_t)((kt_) * 64) * 3072, &kbuf[bufi][(w << 3) * 64]);   \
    gload_lds16(ksrc0 + (size_t)((kt_) * 64 + 32) * 3072,                           \
                &kbuf[bufi][(32 + (w << 3)) * 64]);                                 \
    gload_lds16(vsrc0 + (size_t)((kt_) * 64) * 3072, &vbuf[bufi][w << 9]);          \
    gload_lds16(vsrc0 + (size_t)((kt_) * 64 + 32) * 3072,                           \
                &vbuf[bufi][2048 + (w << 9)]);                                      \
  }

  STAGEKV(0, 0);
  const bf16x8 qf0 = *(const bf16x8*)(qp + g * 8);
  const bf16x8 qf1 = *(const bf16x8*)(qp + 32 + g * 8);
  for (int i = tid; i < 1024; i += 256) {
    sbias[i] = dist_emb[i * kH + h];
    spad[i] = (seqb[i] == kV - 1) ? 1 : 0;
  }

  f32x4 zz = {0.f, 0.f, 0.f, 0.f};
  f32x4 oacc[4];
#pragma unroll
  for (int n = 0; n < 4; ++n) oacc[n] = zz;
  float m_[4], l_[4];
#pragma unroll
  for (int j = 0; j < 4; ++j) { m_[j] = -1e30f; l_[j] = 0.f; }

  __syncthreads();

#define ATT_STEP64(kt_, bz) do {                                                    \
    bf16x8 kf0[4], kf1[4];                                                          \
    _Pragma("unroll")                                                               \
    for (int ns = 0; ns < 4; ++ns) {                                                \
      const int krow = (ns * 16 + lr) * 64;                                         \
      kf0[ns] = *(const bf16x8*)&kbuf[bz][krow + cs0k];                             \
      kf1[ns] = *(const bf16x8*)&kbuf[bz][krow + cs1k];                             \
    }                                                                               \
    f32x4 s_[4];                                                                    \
    _Pragma("unroll")                                                               \
    for (int ns = 0; ns < 4; ++ns) {                                                \
      f32x4 z = zz;                                                                 \
      z = __builtin_amdgcn_mfma_f32_16x16x32_bf16(qf0, kf0[ns], z, 0, 0, 0);        \
      z = __builtin_amdgcn_mfma_f32_16x16x32_bf16(qf1, kf1[ns], z, 0, 0, 0);        \
      s_[ns] = z;                                                                   \
    }                                                                               \
    const int colb = (kt_) * 64 + lr;                                               \
    bool pad[4];                                                                    \
    _Pragma("unroll")                                                               \
    for (int ns = 0; ns < 4; ++ns) pad[ns] = spad[colb + ns * 16] != 0;             \
    float sv[4][4], mj[4];                                                          \
    _Pragma("unroll")                                                               \
    for (int j = 0; j < 4; ++j) {                                                   \
      const int r = q0 + g * 4 + j;                                                 \
      _Pragma("unroll")                                                             \
      for (int ns = 0; ns < 4; ++ns) {                                              \
        const int cc = colb + ns * 16;                                              \
        sv[ns][j] = (cc <= r && !pad[ns]) ? s_[ns][j] * 0.125f + sbias[r - cc]      \
                                          : -1e30f;                                 \
      }                                                                             \
      mj[j] = fmaxf(fmaxf(sv[0][j], sv[1][j]), fmaxf(sv[2][j], sv[3][j]));          \
      mj[j] = fmaxf(mj[j], dppf<0x121>(mj[j]));                                     \
      mj[j] = fmaxf(mj[j], dppf<0x122>(mj[j]));                                     \
      mj[j] = fmaxf(mj[j], dppf<0x124>(mj[j]));                                     \
      mj[j] = fmaxf(mj[j], dppf<0x128>(mj[j]));                                     \
    }                                                                               \
    float corr[4], pv[4][4];                                                        \
    _Pragma("unroll")                                                               \
    for (int j = 0; j < 4; ++j) {                                                   \
      const float mn = fmaxf(m_[j], mj[j]);                                         \
      corr[j] = __expf(m_[j] - mn);                                                 \
      m_[j] = mn;                                                                   \
      _Pragma("unroll")                                                             \
      for (int ns = 0; ns < 4; ++ns) pv[ns][j] = __expf(sv[ns][j] - mn);            \
      float rs = (pv[0][j] + pv[1][j]) + (pv[2][j] + pv[3][j]);                     \
      rs += dppf<0x121>(rs);                                                        \
      rs += dppf<0x122>(rs);                                                        \
      rs += dppf<0x124>(rs);                                                        \
      rs += dppf<0x128>(rs);                                                        \
      l_[j] = l_[j] * corr[j] + rs;                                                 \
    }                                                                               \
    _Pragma("unroll")                                                               \
    for (int n = 0; n < 4; ++n) {                                                   \
      f32x4 t = oacc[n];                                                            \
      t[0] *= corr[0]; t[1] *= corr[1]; t[2] *= corr[2]; t[3] *= corr[3];           \
      oacc[n] = t;                                                                  \
    }                                                                               \
    _Pragma("unroll")                                                               \
    for (int j = 0; j < 4; ++j) {                                                   \
      _Pragma("unroll")                                                             \
      for (int ns = 0; ns < 4; ++ns)                                                \
        pbuf[w][g * 4 + j][ns * 16 + lr] = (bf16_t)pv[ns][j];                       \
    }                                                                               \
    asm volatile("s_waitcnt lgkmcnt(0)" ::: "memory");                              \
    const bf16x4 pa0 = *(const bf16x4*)&pbuf[w][lr][g * 4];                         \
    const bf16x4 pa1 = *(const bf16x4*)&pbuf[w][lr][16 + g * 4];                    \
    const bf16x4 pa2 = *(const bf16x4*)&pbuf[w][lr][32 + g * 4];                    \
    const bf16x4 pa3 = *(const bf16x4*)&pbuf[w][lr][48 + g * 4];                    \
    bf16x8 pfl, pfh;                                                                \
    _Pragma("unroll")                                                               \
    for (int j = 0; j < 4; ++j) {                                                   \
      pfl[j] = pa0[j]; pfl[4 + j] = pa1[j];                                         \
      pfh[j] = pa2[j]; pfh[4 + j] = pa3[j];                                         \
    }                                                                               \
    const unsigned vb0 = lds_u32(&vbuf[bz][0]) + g * 128 + lr * 8;                  \
    u32x2 vt[8], vth[8];                                                            \
    _Pragma("unroll")                                                               \
    for (int n = 0; n < 4; ++n) {                                                   \
      asm volatile("ds_read_b64_tr_b16 %0, %2\n\t"                                  \
                   "ds_read_b64_tr_b16 %1, %2 offset:2048"                          \
                   : "=&v"(vt[n * 2]), "=&v"(vt[n * 2 + 1])                         \
                   : "v"(vb0 + n * 512)                                             \
                   : "memory");                                                     \
      asm volatile("ds_read_b64_tr_b16 %0, %2 offset:4096\n\t"                      \
                   "ds_read_b64_tr_b16 %1, %2 offset:6144"                          \
                   : "=&v"(vth[n * 2]), "=&v"(vth[n * 2 + 1])                       \
                   : "v"(vb0 + n * 512)                                             \
                   : "memory");                                                     \
    }                                                                               \
    asm volatile("s_waitcnt lgkmcnt(0)" ::: "memory");                              \
    __builtin_amdgcn_sched_barrier(0);                                              \
    _Pragma("unroll")                                                               \
    for (int n = 0; n < 4; ++n) {                                                   \
      const bf16x4 v0 = __builtin_bit_cast(bf16x4, vt[n * 2]);                      \
      const bf16x4 v1 = __builtin_bit_cast(bf16x4, vt[n * 2 + 1]);                  \
      bf16x8 vf;                                                                    \
      _Pragma("unroll")                                                             \
      for (int j = 0; j < 4; ++j) { vf[j] = v0[j]; vf[4 + j] = v1[j]; }             \
      oacc[n] = __builtin_amdgcn_mfma_f32_16x16x32_bf16(pfl, vf, oacc[n], 0, 0, 0); \
      const bf16x4 h0 = __builtin_bit_cast(bf16x4, vth[n * 2]);                     \
      const bf16x4 h1 = __builtin_bit_cast(bf16x4, vth[n * 2 + 1]);                 \
      bf16x8 vfh;                                                                   \
      _Pragma("unroll")                                                             \
      for (int j = 0; j < 4; ++j) { vfh[j] = h0[j]; vfh[4 + j] = h1[j]; }           \
      oacc[n] = __builtin_amdgcn_mfma_f32_16x16x32_bf16(pfh, vfh, oacc[n], 0, 0, 0);\
    }                                                                               \
  } while (0)

  for (int kt = 0; kt < nt; kt += 2) {
    if (kt + 1 < nt) STAGEKV(1, kt + 1);
    ATT_STEP64(kt, 0);
    __syncthreads();
    if (kt + 2 < nt) STAGEKV(0, kt + 2);
    if (kt + 1 < nt) ATT_STEP64(kt + 1, 1);
    __syncthreads();
  }
#undef ATT_STEP64
#undef STAGEKV

#pragma unroll
  for (int j = 0; j < 4; ++j) {
    const float inv = 1.0f / l_[j];
    const int r = q0 + g * 4 + j;
    bf16_t* dst = ctx + ((size_t)(b * kS + r)) * kE + h * 64;
#pragma unroll
    for (int n = 0; n < 4; ++n) dst[n * 16 + lr] = (bf16_t)(oacc[n][j] * inv);
  }
}

// ---------------- host ----------------
extern "C" void kernel_launch(void* const* d_in, const int* in_sizes, int n_in,
                              void* d_out, int out_size, void* d_ws, size_t ws_size,
                              hipStream_t stream) {
  (void)in_sizes; (void)n_in; (void)out_size;
  const int* seq = (const int*)d_in[0];
  const float* emb = (const float*)d_in[1];
  const float* pos = (const float*)d_in[2];
  const float* dist = (const float*)d_in[3];
  const float* in_w = (const float*)d_in[4];
  const float* in_b = (const float*)d_in[5];
  const float* out_w = (const float*)d_in[6];
  const float* out_b = (const float*)d_in[7];
  const float* ln1g = (const float*)d_in[8];
  const float* ln1b = (const float*)d_in[9];
  const float* ff1w = (const float*)d_in[10];
  const float* ff1b = (const float*)d_in[11];
  const float* ff2w = (const float*)d_in[12];
  const float* ff2b = (const float*)d_in[13];
  const float* ln2g = (const float*)d_in[14];
  const float* ln2b = (const float*)d_in[15];
  const float* lnfg = (const float*)d_in[16];
  const float* lnfb = (const float*)d_in[17];
  const float* genw = (const float*)d_in[18];
  const float* genb = (const float*)d_in[19];

  char* ws = (char*)d_ws;
  size_t off = 0;
  auto alloc = [&](size_t elems, size_t esz) -> void* {
    void* pp = ws + off;
    off += (elems * esz + 255) & ~(size_t)255;
    return pp;
  };
  bf16_t* w_in = (bf16_t*)alloc((size_t)kL * 3 * kE * kE, 2);
  bf16_t* w_out = (bf16_t*)alloc((size_t)kL * kE * kE, 2);
  bf16_t* w_f1 = (bf16_t*)alloc((size_t)kL * kF * kE, 2);
  bf16_t* w_f2 = (bf16_t*)alloc((size_t)kL * kE * kF, 2);
  bf16_t* w_g = (bf16_t*)alloc((size_t)kV * kE, 2);
  float* x32 = (float*)alloc((size_t)kRows * kE, 4);
  bf16_t* xb = (bf16_t*)alloc((size_t)kRows * kE, 2);
  bf16_t* qkvb = (bf16_t*)alloc((size_t)kRows * 3 * kE, 2);
  bf16_t* ctxb = (bf16_t*)alloc((size_t)kRows * kE, 2);
  bf16_t* tmp4 = (bf16_t*)alloc((size_t)4 * kRows * kE, 2);  // split-K partials
  bf16_t* hb = (bf16_t*)alloc((size_t)kRows * kF, 2);
  if (off > ws_size) return;

  cast_kernel<<<2048, 256, 0, stream>>>(in_w, w_in, kL * 3 * kE * kE / 4);
  cast_kernel<<<2048, 256, 0, stream>>>(out_w, w_out, kL * kE * kE / 4);
  cast_kernel<<<2048, 256, 0, stream>>>(ff1w, w_f1, kL * kF * kE / 4);
  cast_kernel<<<2048, 256, 0, stream>>>(ff2w, w_f2, kL * kE * kF / 4);
  cast_kernel<<<1024, 256, 0, stream>>>(genw, w_g, kV * kE / 4);
  embed_kernel<<<kRows, 256, 0, stream>>>(seq, emb, pos, x32, xb);

  for (int l = 0; l < kL; ++l) {
    // QKV: [4096,1024] x [3072,1024]^T -> bf16 [4096,3072]; 768 blocks
    gemm128_kernel<0><<<dim3(3 * kE / 128, kRows / 128), 256, 0, stream>>>(
        xb, w_in + (size_t)l * 3 * kE * kE, in_b + (size_t)l * 3 * kE, qkvb,
        kE, kE, 3 * kE, kE, 0);
    attn_kernel<<<kB * kH * 16, 256, 0, stream>>>(qkvb, seq, dist, ctxb);
    // proj: split-K x4 (kc=256) -> 4 bf16 partials; 1024 blocks
    gemm128_kernel<3><<<dim3(kE / 128, kRows / 128, 4), 256, 0, stream>>>(
        ctxb, w_out + (size_t)l * kE * kE, nullptr, tmp4,
        kE, kE, kE, 256, (size_t)kRows * kE);
    addln_kernel<2><<<kRows, 256, 0, stream>>>(x32, tmp4, ln1g + (size_t)l * kE,
                                               ln1b + (size_t)l * kE, xb, out_b + (size_t)l * kE);
    // FF1: [4096,1024] x [4096,1024]^T + bias + GELU -> bf16 [4096,4096]; 1024 blocks
    gemm128_kernel<2><<<dim3(kF / 128, kRows / 128), 256, 0, stream>>>(
        xb, w_f1 + (size_t)l * kF * kE, ff1b + (size_t)l * kF, hb,
        kE, kE, kF, kE, 0);
    // FF2: split-K x4 (kc=1024): [4096,4096] x [1024,4096]^T -> 4 bf16 partials; 1024 blocks
    gemm128_kernel<3><<<dim3(kE / 128, kRows / 128, 4), 256, 0, stream>>>(
        hb, w_f2 + (size_t)l * kE * kF, nullptr, tmp4,
        kF, kF, kE, kE, (size_t)kRows * kE);
    addln_kernel<2><<<kRows, 256, 0, stream>>>(x32, tmp4, ln2g + (size_t)l * kE,
                                               ln2b + (size_t)l * kE, xb, ff2b + (size_t)l * kE);
  }
  addln_kernel<1><<<kRows, 256, 0, stream>>>(x32, nullptr, lnfg, lnfb, xb, nullptr);
  gemm128_kernel<1><<<dim3(kV / 128, kRows / 128), 256, 0, stream>>>(
      xb, w_g, genb, (float*)d_out, kE, kE, kV, kE, 0);
}

// Round 8
// 1385.668 us; speedup vs baseline: 2.0326x; 2.0326x over previous
//
#include <hip/hip_runtime.h>
#include <math.h>
#include <stdint.h>

// ---------------- problem constants ----------------
constexpr int kL = 6;
constexpr int kE = 1024;
constexpr int kH = 16;
constexpr int kF = 4096;
constexpr int kV = 1024;
constexpr int kB = 4;
constexpr int kS = 1024;
constexpr int kRows = kB * kS;   // 4096

typedef __bf16 bf16_t;
typedef __bf16 bf16x8 __attribute__((ext_vector_type(8)));
typedef __bf16 bf16x4 __attribute__((ext_vector_type(4)));
typedef float f32x4 __attribute__((ext_vector_type(4)));
typedef unsigned int u32x2 __attribute__((ext_vector_type(2)));

#define AS1 __attribute__((address_space(1)))
#define AS3 __attribute__((address_space(3)))

__device__ __forceinline__ void gload_lds16(const void* g, void* l) {
  __builtin_amdgcn_global_load_lds((const AS1 unsigned int*)g, (AS3 unsigned int*)l, 16, 0, 0);
}

__device__ __forceinline__ unsigned lds_u32(const void* p) {
  return (unsigned)(uintptr_t)p;
}

__device__ __forceinline__ float gelu_f(float x) {
  return 0.5f * x * (1.0f + erff(x * 0.70710678118654752440f));
}

// DPP row-rotate (16-lane granularity). CTRL = 0x120 + n for ROW_ROR:n.
template <int CTRL>
__device__ __forceinline__ float dppf(float v) {
  return __builtin_bit_cast(float, __builtin_amdgcn_update_dpp(
      __builtin_bit_cast(int, v), __builtin_bit_cast(int, v), CTRL, 0xF, 0xF, false));
}

// ---------------- f32 -> bf16 cast ----------------
__global__ void cast_kernel(const float* __restrict__ in, bf16_t* __restrict__ out, int n4) {
  const int stride = gridDim.x * blockDim.x;
  for (int i = blockIdx.x * blockDim.x + threadIdx.x; i < n4; i += stride) {
    const float4 v = *(const float4*)(in + (size_t)i * 4);
    bf16x4 o;
    o[0] = (bf16_t)v.x; o[1] = (bf16_t)v.y; o[2] = (bf16_t)v.z; o[3] = (bf16_t)v.w;
    *(bf16x4*)(out + (size_t)i * 4) = o;
  }
}

// ---------------- embedding ----------------
__global__ void embed_kernel(const int* __restrict__ seq, const float* __restrict__ emb,
                             const float* __restrict__ pos, float* __restrict__ x32,
                             bf16_t* __restrict__ xb) {
  const int r = blockIdx.x;
  const int s = r & 1023;
  const int tok = seq[r];
  const int c = threadIdx.x << 2;
  const float4 e = *(const float4*)(emb + (size_t)tok * kE + c);
  const float4 pz = *(const float4*)(pos + (size_t)s * kE + c);
  float4 v;
  v.x = e.x * 32.0f + pz.x;
  v.y = e.y * 32.0f + pz.y;
  v.z = e.z * 32.0f + pz.z;
  v.w = e.w * 32.0f + pz.w;
  *(float4*)(x32 + (size_t)r * kE + c) = v;
  bf16x4 o;
  o[0] = (bf16_t)v.x; o[1] = (bf16_t)v.y; o[2] = (bf16_t)v.z; o[3] = (bf16_t)v.w;
  *(bf16x4*)(xb + (size_t)r * kE + c) = o;
}

// ---------------- residual add + LayerNorm ----------------
// MODE 0: x32 = LN(x32 + res_bf16), write bf16 copy.
// MODE 1: bf16 out only, no residual (final LN).
// MODE 2: x32 = LN(x32 + sum of 4 bf16 partials + bias2), write bf16 copy.
template <int MODE>
__global__ void addln_kernel(float* __restrict__ x32, const void* __restrict__ res,
                             const float* __restrict__ gg, const float* __restrict__ bb,
                             bf16_t* __restrict__ xb, const float* __restrict__ bias2) {
  __shared__ float red[8];
  const int r = blockIdx.x;
  const int c = threadIdx.x << 2;
  float4 v = *(const float4*)(x32 + (size_t)r * kE + c);
  if (MODE == 0) {
    const bf16x4 t = *(const bf16x4*)((const bf16_t*)res + (size_t)r * kE + c);
    v.x += (float)t[0]; v.y += (float)t[1]; v.z += (float)t[2]; v.w += (float)t[3];
  }
  if (MODE == 2) {
    const bf16_t* p = (const bf16_t*)res;
#pragma unroll
    for (int part = 0; part < 4; ++part) {
      const bf16x4 t = *(const bf16x4*)(p + (size_t)part * kRows * kE + (size_t)r * kE + c);
      v.x += (float)t[0]; v.y += (float)t[1]; v.z += (float)t[2]; v.w += (float)t[3];
    }
    const float4 b2 = *(const float4*)(bias2 + c);
    v.x += b2.x; v.y += b2.y; v.z += b2.z; v.w += b2.w;
  }
  float s = v.x + v.y + v.z + v.w;
  float q = v.x * v.x + v.y * v.y + v.z * v.z + v.w * v.w;
#pragma unroll
  for (int off = 32; off >= 1; off >>= 1) {
    s += __shfl_xor(s, off, 64);
    q += __shfl_xor(q, off, 64);
  }
  const int w = threadIdx.x >> 6, lane = threadIdx.x & 63;
  if (lane == 0) { red[w] = s; red[4 + w] = q; }
  __syncthreads();
  s = red[0] + red[1] + red[2] + red[3];
  q = red[4] + red[5] + red[6] + red[7];
  const float mean = s * (1.0f / 1024.0f);
  const float var = q * (1.0f / 1024.0f) - mean * mean;
  const float rstd = rsqrtf(var + 1e-5f);
  const float4 g4 = *(const float4*)(gg + c);
  const float4 b4 = *(const float4*)(bb + c);
  float4 o;
  o.x = (v.x - mean) * rstd * g4.x + b4.x;
  o.y = (v.y - mean) * rstd * g4.y + b4.y;
  o.z = (v.z - mean) * rstd * g4.z + b4.z;
  o.w = (v.w - mean) * rstd * g4.w + b4.w;
  if (MODE != 1) *(float4*)(x32 + (size_t)r * kE + c) = o;
  bf16x4 ob;
  ob[0] = (bf16_t)o.x; ob[1] = (bf16_t)o.y; ob[2] = (bf16_t)o.z; ob[3] = (bf16_t)o.w;
  *(bf16x4*)(xb + (size_t)r * kE + c) = ob;
}

// ---------------- GEMM 128x128, BK=32, 4 waves (v5: conflict-free LDS) -------------
// REVERTED to the verified R5 kernel (best total: 1405 us). R6 counted-vmcnt was
// null; R7 zero-LDS was -2.4x (strided fragment loads serialize in the VMEM path).
// Layout: each 128x32 tile packed as LDS [64 row'][64 elems]; physical granule =
// logical ^ (row'&7); linear LDS dest with inverse swizzle folded into the global
// source address (rule 21); ds_read_b128 applies the same XOR (2-way max = free).
// 16 KB LDS, __launch_bounds__(256,4) -> 4 blocks/CU.
// EPI: 0 = bias->bf16, 1 = bias->f32 (logits), 2 = bias+GELU->bf16,
//      3 = no-bias->bf16 partial at Cv + blockIdx.z*zstride.
template <int EPI>
__launch_bounds__(256, 4)
__global__ void gemm128_kernel(const bf16_t* __restrict__ A, const bf16_t* __restrict__ Bt,
                               const float* __restrict__ bias, void* __restrict__ Cv,
                               int ldA, int ldB, int ldC, int kc, size_t zstride) {
  __shared__ bf16_t lA[64 * 64];
  __shared__ bf16_t lB[64 * 64];
  const int tid = threadIdx.x;
  const int w = tid >> 6;
  const int lane = tid & 63;
  const int g = lane >> 4;
  const int lr = lane & 15;

  // T1: XCD-aware bijective swizzle over (x,y); all grids have nwg % 8 == 0.
  const int nwg = gridDim.x * gridDim.y;
  const int lin = blockIdx.y * gridDim.x + blockIdx.x;
  const int cpx = nwg >> 3;
  const int swz = (lin & 7) * cpx + (lin >> 3);
  const int bx = swz % gridDim.x, by = swz / gridDim.x;
  const int bm0 = by << 7;
  const int bn0 = bx << 7;
  const int k0 = blockIdx.z * kc;
  const int wm = (w >> 1) << 6;
  const int wn = (w & 1) << 6;

  // staging source: chunk c (1KB = rows' 8c..8c+7) is linear in LDS; lane l of
  // chunk c supplies logical granule pg = (l&7)^(l>>3) of row' 8c+(l>>3), i.e.
  // matrix row 16c + 2*(l>>3) + (pg>>2), k-granule (pg&3).
  const int ln8 = lane >> 3, l8 = lane & 7;
  const int pg = l8 ^ ln8;
  const int arow0 = (w << 5) + (ln8 << 1) + (pg >> 2);   // chunk 2w   -> rows 32w..32w+15
  const int arow1 = arow0 + 16;                          // chunk 2w+1 -> rows 32w+16..32w+31
  const int kpo = (pg & 3) << 3;
  const bf16_t* srcA0 = A + (size_t)(bm0 + arow0) * ldA + k0 + kpo;
  const bf16_t* srcA1 = A + (size_t)(bm0 + arow1) * ldA + k0 + kpo;
  const bf16_t* srcB0 = Bt + (size_t)(bn0 + arow0) * ldB + k0 + kpo;
  const bf16_t* srcB1 = Bt + (size_t)(bn0 + arow1) * ldB + k0 + kpo;
  bf16_t* dA0 = lA + (w << 10);
  bf16_t* dA1 = lA + (w << 10) + 512;
  bf16_t* dB0 = lB + (w << 10);
  bf16_t* dB1 = lB + (w << 10) + 512;

  f32x4 zz = {0.f, 0.f, 0.f, 0.f};
  f32x4 acc[4][4];
#pragma unroll
  for (int i = 0; i < 4; ++i)
#pragma unroll
    for (int j = 0; j < 4; ++j) acc[i][j] = zz;

  // fragment read offsets (elements): matrix row r, k-granule g ->
  // row' = r>>1, logical granule (r&1)*4+g, physical ^= (row'&7)
  int paoff[4], pboff[4];
#pragma unroll
  for (int i = 0; i < 4; ++i) {
    const int ra = wm + i * 16 + lr;
    paoff[i] = ((ra >> 1) << 6) + (((((ra & 1) << 2) + g) ^ ((ra >> 1) & 7)) << 3);
    const int rb = wn + i * 16 + lr;
    pboff[i] = ((rb >> 1) << 6) + (((((rb & 1) << 2) + g) ^ ((rb >> 1) & 7)) << 3);
  }

  const int NT = kc >> 5;
  for (int t = 0; t < NT; ++t) {
    gload_lds16(srcA0, dA0);
    gload_lds16(srcA1, dA1);
    gload_lds16(srcB0, dB0);
    gload_lds16(srcB1, dB1);
    srcA0 += 32; srcA1 += 32; srcB0 += 32; srcB1 += 32;
    __syncthreads();
    bf16x8 a[4], b[4];
#pragma unroll
    for (int i = 0; i < 4; ++i) a[i] = *(const bf16x8*)&lA[paoff[i]];
#pragma unroll
    for (int i = 0; i < 4; ++i) b[i] = *(const bf16x8*)&lB[pboff[i]];
#pragma unroll
    for (int i = 0; i < 4; ++i)
#pragma unroll
      for (int j = 0; j < 4; ++j)
        acc[i][j] = __builtin_amdgcn_mfma_f32_16x16x32_bf16(a[i], b[j], acc[i][j], 0, 0, 0);
    __syncthreads();
  }

  // epilogue: C/D layout col = lane&15, row = (lane>>4)*4 + reg
  bf16_t* outb = (bf16_t*)Cv;
  if (EPI == 3) outb += (size_t)blockIdx.z * zstride;
#pragma unroll
  for (int i = 0; i < 4; ++i) {
#pragma unroll
    for (int j = 0; j < 4; ++j) {
      const int col = bn0 + wn + j * 16 + lr;
      float bv = 0.0f;
      if (EPI != 3) bv = bias[col];
#pragma unroll
      for (int rg = 0; rg < 4; ++rg) {
        const int row = bm0 + wm + i * 16 + g * 4 + rg;
        float v = acc[i][j][rg] + bv;
        if (EPI == 2) v = gelu_f(v);
        if (EPI == 1) {
          ((float*)Cv)[(size_t)row * ldC + col] = v;
        } else {
          outb[(size_t)row * ldC + col] = (bf16_t)v;
        }
      }
    }
  }
}

// ---------------- fused causal attention with relative-distance bias ----------------
// v4: v3 (KVBLK=64, DPP softmax, LDS K+V, heavy-first) + two chain cuts:
//  - T13 defer-max: skip the 16-lane max tree + corr exps + oacc rescale when
//    __all(per-lane max <= m_ + 8). P bounded by e^8 (fine in f32/bf16). First
//    step always takes the full path (m_ = -1e30), so m_ is finite afterwards.
//  - deferred l-sum: l_ kept as per-lane partials (sum is linear; corr is uniform
//    within each 16-lane group after the max tree) -> the 4-level DPP sum tree
//    runs ONCE in the epilogue instead of every step.
__launch_bounds__(256, 3)
__global__ void attn_kernel(const bf16_t* __restrict__ qkv, const int* __restrict__ seq,
                            const float* __restrict__ dist_emb, bf16_t* __restrict__ ctx) {
  __shared__ float sbias[1024];
  __shared__ unsigned char spad[1024];
  __shared__ bf16_t kbuf[2][64 * 64];
  __shared__ bf16_t vbuf[2][4096];
  __shared__ bf16_t pbuf[4][16][72];
  const int tid = threadIdx.x;
  const int w = tid >> 6, lane = tid & 63, g = lane >> 4, lr = lane & 15;
  const int bid = blockIdx.x;
  const int qt = 15 - (bid >> 6);      // heavy blocks dispatch first
  const int h = bid & 15, b = (bid >> 4) & 3;

  const int q0 = qt * 64 + w * 16;
  const bf16_t* qp = qkv + ((size_t)(b * kS + q0 + lr)) * 3072 + h * 64;

  // V staging source (tr-read layout, 32-row half granularity)
  const int p = (w * 64 + lane) * 16;
  const int s_kv = ((p >> 11) << 4) + ((p >> 5) & 15);
  const int s_dv = (((p >> 9) & 3) << 4) + ((p & 31) >> 1);
  const bf16_t* vsrc0 = qkv + ((size_t)(b * kS + s_kv)) * 3072 + 2048 + h * 64 + s_dv;

  // K staging source (xor-swizzle pre-applied to global column granule)
  const int klrow = (w << 3) + (lane >> 3);
  const int kscol = ((lane & 7) ^ (lane >> 3)) << 3;
  const bf16_t* ksrc0 = qkv + ((size_t)(b * kS + klrow)) * 3072 + 1024 + h * 64 + kscol;

  // swizzled K ds_read column offsets (elements)
  const int cs0k = (g ^ (lr & 7)) << 3;
  const int cs1k = ((4 + g) ^ (lr & 7)) << 3;

  const int* seqb = seq + b * kS;
  const int nt = qt + 1;

#define STAGEKV(bufi, kt_) {                                                        \
    gload_lds16(ksrc0 + (size_t)((kt_) * 64) * 3072, &kbuf[bufi][(w << 3) * 64]);   \
    gload_lds16(ksrc0 + (size_t)((kt_) * 64 + 32) * 3072,                           \
                &kbuf[bufi][(32 + (w << 3)) * 64]);                                 \
    gload_lds16(vsrc0 + (size_t)((kt_) * 64) * 3072, &vbuf[bufi][w << 9]);          \
    gload_lds16(vsrc0 + (size_t)((kt_) * 64 + 32) * 3072,                           \
                &vbuf[bufi][2048 + (w << 9)]);                                      \
  }

  STAGEKV(0, 0);
  const bf16x8 qf0 = *(const bf16x8*)(qp + g * 8);
  const bf16x8 qf1 = *(const bf16x8*)(qp + 32 + g * 8);
  for (int i = tid; i < 1024; i += 256) {
    sbias[i] = dist_emb[i * kH + h];
    spad[i] = (seqb[i] == kV - 1) ? 1 : 0;
  }

  f32x4 zz = {0.f, 0.f, 0.f, 0.f};
  f32x4 oacc[4];
#pragma unroll
  for (int n = 0; n < 4; ++n) oacc[n] = zz;
  float m_[4], l_[4];
#pragma unroll
  for (int j = 0; j < 4; ++j) { m_[j] = -1e30f; l_[j] = 0.f; }

  __syncthreads();

#define ATT_STEP64(kt_, bz) do {                                                    \
    bf16x8 kf0[4], kf1[4];                                                          \
    _Pragma("unroll")                                                               \
    for (int ns = 0; ns < 4; ++ns) {                                                \
      const int krow = (ns * 16 + lr) * 64;                                         \
      kf0[ns] = *(const bf16x8*)&kbuf[bz][krow + cs0k];                             \
      kf1[ns] = *(const bf16x8*)&kbuf[bz][krow + cs1k];                             \
    }                                                                               \
    f32x4 s_[4];                                                                    \
    _Pragma("unroll")                                                               \
    for (int ns = 0; ns < 4; ++ns) {                                                \
      f32x4 z = zz;                                                                 \
      z = __builtin_amdgcn_mfma_f32_16x16x32_bf16(qf0, kf0[ns], z, 0, 0, 0);        \
      z = __builtin_amdgcn_mfma_f32_16x16x32_bf16(qf1, kf1[ns], z, 0, 0, 0);        \
      s_[ns] = z;                                                                   \
    }                                                                               \
    const int colb = (kt_) * 64 + lr;                                               \
    bool pad[4];                                                                    \
    _Pragma("unroll")                                                               \
    for (int ns = 0; ns < 4; ++ns) pad[ns] = spad[colb + ns * 16] != 0;             \
    float sv[4][4], lmax[4];                                                        \
    _Pragma("unroll")                                                               \
    for (int j = 0; j < 4; ++j) {                                                   \
      const int r = q0 + g * 4 + j;                                                 \
      _Pragma("unroll")                                                             \
      for (int ns = 0; ns < 4; ++ns) {                                              \
        const int cc = colb + ns * 16;                                              \
        sv[ns][j] = (cc <= r && !pad[ns]) ? s_[ns][j] * 0.125f + sbias[r - cc]      \
                                          : -1e30f;                                 \
      }                                                                             \
      lmax[j] = fmaxf(fmaxf(sv[0][j], sv[1][j]), fmaxf(sv[2][j], sv[3][j]));        \
    }                                                                               \
    /* T13 defer-max: full path only when some lane's max exceeds m_ + 8 */         \
    const bool okk = (lmax[0] <= m_[0] + 8.0f) && (lmax[1] <= m_[1] + 8.0f) &&      \
                     (lmax[2] <= m_[2] + 8.0f) && (lmax[3] <= m_[3] + 8.0f);        \
    if (!__all((int)okk)) {                                                         \
      float mj[4], corr[4];                                                         \
      _Pragma("unroll")                                                             \
      for (int j = 0; j < 4; ++j) {                                                 \
        mj[j] = lmax[j];                                                            \
        mj[j] = fmaxf(mj[j], dppf<0x121>(mj[j]));                                   \
        mj[j] = fmaxf(mj[j], dppf<0x122>(mj[j]));                                   \
        mj[j] = fmaxf(mj[j], dppf<0x124>(mj[j]));                                   \
        mj[j] = fmaxf(mj[j], dppf<0x128>(mj[j]));                                   \
        const float mn = fmaxf(m_[j], mj[j]);                                       \
        corr[j] = __expf(m_[j] - mn);                                               \
        m_[j] = mn;                                                                 \
        l_[j] *= corr[j];                                                           \
      }                                                                             \
      _Pragma("unroll")                                                             \
      for (int n = 0; n < 4; ++n) {                                                 \
        f32x4 t = oacc[n];                                                          \
        t[0] *= corr[0]; t[1] *= corr[1]; t[2] *= corr[2]; t[3] *= corr[3];         \
        oacc[n] = t;                                                                \
      }                                                                             \
    }                                                                               \
    float pv[4][4];                                                                 \
    _Pragma("unroll")                                                               \
    for (int j = 0; j < 4; ++j) {                                                   \
      _Pragma("unroll")                                                             \
      for (int ns = 0; ns < 4; ++ns) pv[ns][j] = __expf(sv[ns][j] - m_[j]);         \
      l_[j] += (pv[0][j] + pv[1][j]) + (pv[2][j] + pv[3][j]);  /* per-lane partial */\
    }                                                                               \
    _Pragma("unroll")                                                               \
    for (int j = 0; j < 4; ++j) {                                                   \
      _Pragma("unroll")                                                             \
      for (int ns = 0; ns < 4; ++ns)                                                \
        pbuf[w][g * 4 + j][ns * 16 + lr] = (bf16_t)pv[ns][j];                       \
    }                                                                               \
    asm volatile("s_waitcnt lgkmcnt(0)" ::: "memory");                              \
    const bf16x4 pa0 = *(const bf16x4*)&pbuf[w][lr][g * 4];                         \
    const bf16x4 pa1 = *(const bf16x4*)&pbuf[w][lr][16 + g * 4];                    \
    const bf16x4 pa2 = *(const bf16x4*)&pbuf[w][lr][32 + g * 4];                    \
    const bf16x4 pa3 = *(const bf16x4*)&pbuf[w][lr][48 + g * 4];                    \
    bf16x8 pfl, pfh;                                                                \
    _Pragma("unroll")                                                               \
    for (int j = 0; j < 4; ++j) {                                                   \
      pfl[j] = pa0[j]; pfl[4 + j] = pa1[j];                                         \
      pfh[j] = pa2[j]; pfh[4 + j] = pa3[j];                                         \
    }                                                                               \
    const unsigned vb0 = lds_u32(&vbuf[bz][0]) + g * 128 + lr * 8;                  \
    u32x2 vt[8], vth[8];                                                            \
    _Pragma("unroll")                                                               \
    for (int n = 0; n < 4; ++n) {                                                   \
      asm volatile("ds_read_b64_tr_b16 %0, %2\n\t"                                  \
                   "ds_read_b64_tr_b16 %1, %2 offset:2048"                          \
                   : "=&v"(vt[n * 2]), "=&v"(vt[n * 2 + 1])                         \
                   : "v"(vb0 + n * 512)                                             \
                   : "memory");                                                     \
      asm volatile("ds_read_b64_tr_b16 %0, %2 offset:4096\n\t"                      \
                   "ds_read_b64_tr_b16 %1, %2 offset:6144"                          \
                   : "=&v"(vth[n * 2]), "=&v"(vth[n * 2 + 1])                       \
                   : "v"(vb0 + n * 512)                                             \
                   : "memory");                                                     \
    }                                                                               \
    asm volatile("s_waitcnt lgkmcnt(0)" ::: "memory");                              \
    __builtin_amdgcn_sched_barrier(0);                                              \
    _Pragma("unroll")                                                               \
    for (int n = 0; n < 4; ++n) {                                                   \
      const bf16x4 v0 = __builtin_bit_cast(bf16x4, vt[n * 2]);                      \
      const bf16x4 v1 = __builtin_bit_cast(bf16x4, vt[n * 2 + 1]);                  \
      bf16x8 vf;                                                                    \
      _Pragma("unroll")                                                             \
      for (int j = 0; j < 4; ++j) { vf[j] = v0[j]; vf[4 + j] = v1[j]; }             \
      oacc[n] = __builtin_amdgcn_mfma_f32_16x16x32_bf16(pfl, vf, oacc[n], 0, 0, 0); \
      const bf16x4 h0 = __builtin_bit_cast(bf16x4, vth[n * 2]);                     \
      const bf16x4 h1 = __builtin_bit_cast(bf16x4, vth[n * 2 + 1]);                 \
      bf16x8 vfh;                                                                   \
      _Pragma("unroll")                                                             \
      for (int j = 0; j < 4; ++j) { vfh[j] = h0[j]; vfh[4 + j] = h1[j]; }           \
      oacc[n] = __builtin_amdgcn_mfma_f32_16x16x32_bf16(pfh, vfh, oacc[n], 0, 0, 0);\
    }                                                                               \
  } while (0)

  for (int kt = 0; kt < nt; kt += 2) {
    if (kt + 1 < nt) STAGEKV(1, kt + 1);
    ATT_STEP64(kt, 0);
    __syncthreads();
    if (kt + 2 < nt) STAGEKV(0, kt + 2);
    if (kt + 1 < nt) ATT_STEP64(kt + 1, 1);
    __syncthreads();
  }
#undef ATT_STEP64
#undef STAGEKV

  // deferred l-sum: one 4-level DPP tree over the 16-lane group, then normalize.
#pragma unroll
  for (int j = 0; j < 4; ++j) {
    l_[j] += dppf<0x121>(l_[j]);
    l_[j] += dppf<0x122>(l_[j]);
    l_[j] += dppf<0x124>(l_[j]);
    l_[j] += dppf<0x128>(l_[j]);
  }
#pragma unroll
  for (int j = 0; j < 4; ++j) {
    const float inv = 1.0f / l_[j];
    const int r = q0 + g * 4 + j;
    bf16_t* dst = ctx + ((size_t)(b * kS + r)) * kE + h * 64;
#pragma unroll
    for (int n = 0; n < 4; ++n) dst[n * 16 + lr] = (bf16_t)(oacc[n][j] * inv);
  }
}

// ---------------- host ----------------
extern "C" void kernel_launch(void* const* d_in, const int* in_sizes, int n_in,
                              void* d_out, int out_size, void* d_ws, size_t ws_size,
                              hipStream_t stream) {
  (void)in_sizes; (void)n_in; (void)out_size;
  const int* seq = (const int*)d_in[0];
  const float* emb = (const float*)d_in[1];
  const float* pos = (const float*)d_in[2];
  const float* dist = (const float*)d_in[3];
  const float* in_w = (const float*)d_in[4];
  const float* in_b = (const float*)d_in[5];
  const float* out_w = (const float*)d_in[6];
  const float* out_b = (const float*)d_in[7];
  const float* ln1g = (const float*)d_in[8];
  const float* ln1b = (const float*)d_in[9];
  const float* ff1w = (const float*)d_in[10];
  const float* ff1b = (const float*)d_in[11];
  const float* ff2w = (const float*)d_in[12];
  const float* ff2b = (const float*)d_in[13];
  const float* ln2g = (const float*)d_in[14];
  const float* ln2b = (const float*)d_in[15];
  const float* lnfg = (const float*)d_in[16];
  const float* lnfb = (const float*)d_in[17];
  const float* genw = (const float*)d_in[18];
  const float* genb = (const float*)d_in[19];

  char* ws = (char*)d_ws;
  size_t off = 0;
  auto alloc = [&](size_t elems, size_t esz) -> void* {
    void* pp = ws + off;
    off += (elems * esz + 255) & ~(size_t)255;
    return pp;
  };
  bf16_t* w_in = (bf16_t*)alloc((size_t)kL * 3 * kE * kE, 2);
  bf16_t* w_out = (bf16_t*)alloc((size_t)kL * kE * kE, 2);
  bf16_t* w_f1 = (bf16_t*)alloc((size_t)kL * kF * kE, 2);
  bf16_t* w_f2 = (bf16_t*)alloc((size_t)kL * kE * kF, 2);
  bf16_t* w_g = (bf16_t*)alloc((size_t)kV * kE, 2);
  float* x32 = (float*)alloc((size_t)kRows * kE, 4);
  bf16_t* xb = (bf16_t*)alloc((size_t)kRows * kE, 2);
  bf16_t* qkvb = (bf16_t*)alloc((size_t)kRows * 3 * kE, 2);
  bf16_t* ctxb = (bf16_t*)alloc((size_t)kRows * kE, 2);
  bf16_t* tmp4 = (bf16_t*)alloc((size_t)4 * kRows * kE, 2);  // split-K partials
  bf16_t* hb = (bf16_t*)alloc((size_t)kRows * kF, 2);
  if (off > ws_size) return;

  cast_kernel<<<2048, 256, 0, stream>>>(in_w, w_in, kL * 3 * kE * kE / 4);
  cast_kernel<<<2048, 256, 0, stream>>>(out_w, w_out, kL * kE * kE / 4);
  cast_kernel<<<2048, 256, 0, stream>>>(ff1w, w_f1, kL * kF * kE / 4);
  cast_kernel<<<2048, 256, 0, stream>>>(ff2w, w_f2, kL * kE * kF / 4);
  cast_kernel<<<1024, 256, 0, stream>>>(genw, w_g, kV * kE / 4);
  embed_kernel<<<kRows, 256, 0, stream>>>(seq, emb, pos, x32, xb);

  for (int l = 0; l < kL; ++l) {
    // QKV: [4096,1024] x [3072,1024]^T -> bf16 [4096,3072]; 768 blocks
    gemm128_kernel<0><<<dim3(3 * kE / 128, kRows / 128), 256, 0, stream>>>(
        xb, w_in + (size_t)l * 3 * kE * kE, in_b + (size_t)l * 3 * kE, qkvb,
        kE, kE, 3 * kE, kE, 0);
    attn_kernel<<<kB * kH * 16, 256, 0, stream>>>(qkvb, seq, dist, ctxb);
    // proj: split-K x4 (kc=256) -> 4 bf16 partials; 1024 blocks
    gemm128_kernel<3><<<dim3(kE / 128, kRows / 128, 4), 256, 0, stream>>>(
        ctxb, w_out + (size_t)l * kE * kE, nullptr, tmp4,
        kE, kE, kE, 256, (size_t)kRows * kE);
    addln_kernel<2><<<kRows, 256, 0, stream>>>(x32, tmp4, ln1g + (size_t)l * kE,
                                               ln1b + (size_t)l * kE, xb, out_b + (size_t)l * kE);
    // FF1: [4096,1024] x [4096,1024]^T + bias + GELU -> bf16 [4096,4096]; 1024 blocks
    gemm128_kernel<2><<<dim3(kF / 128, kRows / 128), 256, 0, stream>>>(
        xb, w_f1 + (size_t)l * kF * kE, ff1b + (size_t)l * kF, hb,
        kE, kE, kF, kE, 0);
    // FF2: split-K x4 (kc=1024): [4096,4096] x [1024,4096]^T -> 4 bf16 partials; 1024 blocks
    gemm128_kernel<3><<<dim3(kE / 128, kRows / 128, 4), 256, 0, stream>>>(
        hb, w_f2 + (size_t)l * kE * kF, nullptr, tmp4,
        kF, kF, kE, kE, (size_t)kRows * kE);
    addln_kernel<2><<<kRows, 256, 0, stream>>>(x32, tmp4, ln2g + (size_t)l * kE,
                                               ln2b + (size_t)l * kE, xb, ff2b + (size_t)l * kE);
  }
  addln_kernel<1><<<kRows, 256, 0, stream>>>(x32, nullptr, lnfg, lnfb, xb, nullptr);
  gemm128_kernel<1><<<dim3(kV / 128, kRows / 128), 256, 0, stream>>>(
      xb, w_g, genb, (float*)d_out, kE, kE, kV, kE, 0);
}